// Round 5
// baseline (698.032 us; speedup 1.0000x reference)
//
#include <hip/hip_runtime.h>
#include <math.h>

#define HH 128   // hidden dim (both layers) == input F
#define PS 16    // pool slices per graph

__device__ __forceinline__ float dot4(float4 a, float4 b){
  return a.x*b.x + a.y*b.y + a.z*b.z + a.w*b.w;
}

// ---------------------------------------------------------------------------
// GEMM v3: out = X @ W.T + b for one of {K,Q,V,skip} (blockIdx.y).
// Tile: BM=128 rows x 128 cols, BK=32 k-chunks (4 chunks of K=128).
// 256 threads, each owns an 8x8 register tile -> pure v_fma_f32 chains.
// LDS: sX[128][32], sW[128][32] (32 KB), XOR-swizzled float4 slots:
//   slot p = (kq + (row>>3)) & 7  -> a-reads conflict-free across ty,
//   w-reads 2-way (free). No padding.
// ---------------------------------------------------------------------------
template<bool RELU>
__global__ __launch_bounds__(256, 3) void gemm_tile(
    const float* __restrict__ X,
    const float* __restrict__ Wk, const float* __restrict__ bk,
    const float* __restrict__ Wq, const float* __restrict__ bq,
    const float* __restrict__ Wv, const float* __restrict__ bv,
    const float* __restrict__ Ws, const float* __restrict__ bs,
    float* __restrict__ Ko, float* __restrict__ Qo,
    float* __restrict__ Vo, float* __restrict__ So, int n)
{
  __shared__ float sX[128 * 32];
  __shared__ float sW[128 * 32];

  const int m = blockIdx.y;
  const float* W; const float* B; float* D;
  if (m == 0){ W = Wk; B = bk; D = Ko; }
  else if (m == 1){ W = Wq; B = bq; D = Qo; }
  else if (m == 2){ W = Wv; B = bv; D = Vo; }
  else { W = Ws; B = bs; D = So; }

  const int tid = threadIdx.x;
  const int tx = tid & 15;        // col group: cols tx*8 .. tx*8+7
  const int ty = tid >> 4;        // row group: rows ty*8 .. ty*8+7
  const int row0 = blockIdx.x * 128;

  float acc[8][8];
#pragma unroll
  for (int i = 0; i < 8; ++i)
#pragma unroll
    for (int j = 0; j < 8; ++j) acc[i][j] = 0.f;

  for (int kc = 0; kc < 4; ++kc){
    // ---- stage X chunk: 128 rows x 8 float4 (swizzled slots) ----
#pragma unroll
    for (int it = 0; it < 4; ++it){
      int fi = tid + it * 256;
      int r = fi >> 3, kq = fi & 7;
      int gr = row0 + r;
      float4 v = make_float4(0.f, 0.f, 0.f, 0.f);
      if (gr < n){
        v = ((const float4*)X)[(size_t)gr * 32 + kc * 8 + kq];
        if (RELU){
          v.x = fmaxf(v.x, 0.f); v.y = fmaxf(v.y, 0.f);
          v.z = fmaxf(v.z, 0.f); v.w = fmaxf(v.w, 0.f);
        }
      }
      *(float4*)&sX[r * 32 + (((kq + (r >> 3)) & 7) << 2)] = v;
    }
    // ---- stage W chunk: 128 cols x 8 float4 (swizzled slots) ----
#pragma unroll
    for (int it = 0; it < 4; ++it){
      int fi = tid + it * 256;
      int c = fi >> 3, kq = fi & 7;
      float4 v = ((const float4*)W)[c * 32 + kc * 8 + kq];
      *(float4*)&sW[c * 32 + (((kq + (c >> 3)) & 7) << 2)] = v;
    }
    __syncthreads();

    // ---- compute: 8 k-steps of 4 ----
#pragma unroll
    for (int kq = 0; kq < 8; ++kq){
      const int pa = ((kq + ty) & 7) << 2;
      const int pw = ((kq + tx) & 7) << 2;
      float4 a[8], w[8];
#pragma unroll
      for (int i = 0; i < 8; ++i)
        a[i] = *(const float4*)&sX[(ty * 8 + i) * 32 + pa];
#pragma unroll
      for (int j = 0; j < 8; ++j)
        w[j] = *(const float4*)&sW[(tx * 8 + j) * 32 + pw];
#pragma unroll
      for (int i = 0; i < 8; ++i)
#pragma unroll
        for (int j = 0; j < 8; ++j){
          float s = acc[i][j];
          s = fmaf(a[i].x, w[j].x, s);
          s = fmaf(a[i].y, w[j].y, s);
          s = fmaf(a[i].z, w[j].z, s);
          s = fmaf(a[i].w, w[j].w, s);
          acc[i][j] = s;
        }
    }
    __syncthreads();
  }

  // ---- epilogue: bias + store (2x float4 per row) ----
  float4 b0 = ((const float4*)B)[tx * 2];
  float4 b1 = ((const float4*)B)[tx * 2 + 1];
#pragma unroll
  for (int i = 0; i < 8; ++i){
    int gr = row0 + ty * 8 + i;
    if (gr < n){
      float4 o0, o1;
      o0.x = acc[i][0] + b0.x; o0.y = acc[i][1] + b0.y;
      o0.z = acc[i][2] + b0.z; o0.w = acc[i][3] + b0.w;
      o1.x = acc[i][4] + b1.x; o1.y = acc[i][5] + b1.y;
      o1.z = acc[i][6] + b1.z; o1.w = acc[i][7] + b1.w;
      float4* dst = (float4*)(D + (size_t)gr * HH + tx * 8);
      dst[0] = o0;
      dst[1] = o1;
    }
  }
}

// ---------------------------------------------------------------------------
// CSR build
// ---------------------------------------------------------------------------
__global__ void zero_int(int* __restrict__ p, int n){
  int i = blockIdx.x * blockDim.x + threadIdx.x;
  if (i < n) p[i] = 0;
}

__global__ void hist_dst(const int* __restrict__ ei, int E, int* __restrict__ cnt){
  int e = blockIdx.x * blockDim.x + threadIdx.x;
  if (e < E) atomicAdd(&cnt[ei[E + e]], 1);
}

__global__ __launch_bounds__(256) void scan1(const int* __restrict__ cnt, int n,
                                             int* __restrict__ excl, int* __restrict__ bsum){
  __shared__ int s[256];
  int t = threadIdx.x;
  int i = blockIdx.x * 256 + t;
  int v = (i < n) ? cnt[i] : 0;
  s[t] = v;
  __syncthreads();
  for (int off = 1; off < 256; off <<= 1){
    int u = (t >= off) ? s[t - off] : 0;
    __syncthreads();
    s[t] += u;
    __syncthreads();
  }
  if (i < n) excl[i] = s[t] - v;
  if (t == 255) bsum[blockIdx.x] = s[255];
}

__global__ __launch_bounds__(256) void scan2(int* __restrict__ bsum, int nb){
  __shared__ int s[256];
  int t = threadIdx.x;
  int v = (t < nb) ? bsum[t] : 0;
  s[t] = v;
  __syncthreads();
  for (int off = 1; off < 256; off <<= 1){
    int u = (t >= off) ? s[t - off] : 0;
    __syncthreads();
    s[t] += u;
    __syncthreads();
  }
  if (t < nb) bsum[t] = s[t] - v;
}

__global__ void scan3(int* __restrict__ row_start, const int* __restrict__ bsum,
                      int n, int E, int* __restrict__ cursor){
  int i = blockIdx.x * blockDim.x + threadIdx.x;
  if (i < n){
    int v = row_start[i] + bsum[i >> 8];
    row_start[i] = v;
    cursor[i] = v;
  }
  if (i == n) row_start[n] = E;
}

__global__ void scatter_src(const int* __restrict__ ei, int E,
                            int* __restrict__ cursor, int* __restrict__ csr_src){
  int e = blockIdx.x * blockDim.x + threadIdx.x;
  if (e < E){
    int d = ei[E + e];
    int pos = atomicAdd(&cursor[d], 1);
    csr_src[pos] = ei[e];
  }
}

// ---------------------------------------------------------------------------
// Node-centric aggregate: one wave per dst node, float2 per lane.
// ---------------------------------------------------------------------------
__global__ __launch_bounds__(256) void node_agg(
    const float* __restrict__ Kx, const float* __restrict__ Qx,
    const float* __restrict__ Vx, const float* __restrict__ Sx,
    const int* __restrict__ row_start, const int* __restrict__ csr_src,
    int n, float* __restrict__ H)
{
  int w = blockIdx.x * 4 + (threadIdx.x >> 6);
  w = __builtin_amdgcn_readfirstlane(w);
  if (w >= n) return;
  int lane = threadIdx.x & 63;

  float2 kd = ((const float2*)(Kx + (size_t)w * HH))[lane];
  float ax = 0.f, ay = 0.f;
  int j = row_start[w];
  const int jend = row_start[w + 1];
  for (; j + 1 < jend; j += 2){
    int sA = csr_src[j], sB = csr_src[j + 1];
    float2 qa = ((const float2*)(Qx + (size_t)sA * HH))[lane];
    float2 va = ((const float2*)(Vx + (size_t)sA * HH))[lane];
    float2 qb = ((const float2*)(Qx + (size_t)sB * HH))[lane];
    float2 vb = ((const float2*)(Vx + (size_t)sB * HH))[lane];
    float gax = 1.f / (1.f + __expf(-(kd.x + qa.x)));
    float gay = 1.f / (1.f + __expf(-(kd.y + qa.y)));
    float gbx = 1.f / (1.f + __expf(-(kd.x + qb.x)));
    float gby = 1.f / (1.f + __expf(-(kd.y + qb.y)));
    ax += gax * va.x + gbx * vb.x;
    ay += gay * va.y + gby * vb.y;
  }
  if (j < jend){
    int sA = csr_src[j];
    float2 qa = ((const float2*)(Qx + (size_t)sA * HH))[lane];
    float2 va = ((const float2*)(Vx + (size_t)sA * HH))[lane];
    ax += va.x / (1.f + __expf(-(kd.x + qa.x)));
    ay += va.y / (1.f + __expf(-(kd.y + qa.y)));
  }
  float2 sk = ((const float2*)(Sx + (size_t)w * HH))[lane];
  float2 o; o.x = ax + sk.x; o.y = ay + sk.y;
  ((float2*)(H + (size_t)w * HH))[lane] = o;
}

// ---------------------------------------------------------------------------
// Pool, two-phase.
// ---------------------------------------------------------------------------
__global__ __launch_bounds__(256) void pool_partial(
    const float* __restrict__ Hn, const int* __restrict__ batch,
    int n, float* __restrict__ pmax, float* __restrict__ psum)
{
  int g = blockIdx.x;
  int s = blockIdx.y;
  int lo = 0, hi = n;
  while (lo < hi){ int mid = (lo + hi) >> 1; if (batch[mid] < g) lo = mid + 1; else hi = mid; }
  int s0 = lo;
  lo = s0; hi = n;
  while (lo < hi){ int mid = (lo + hi) >> 1; if (batch[mid] < g + 1) lo = mid + 1; else hi = mid; }
  int e0 = lo;

  int len = e0 - s0;
  int a0 = s0 + (int)(((long long)len * s) / PS);
  int a1 = s0 + (int)(((long long)len * (s + 1)) / PS);

  int t = threadIdx.x;
  int f = t & 127;
  int half = t >> 7;
  float mx = -INFINITY;
  float sm = 0.f;
  for (int i = a0 + half; i < a1; i += 2){
    float v = Hn[(size_t)i * HH + f];
    mx = fmaxf(mx, v);
    sm += v;
  }
  __shared__ float smx[256], ssm[256];
  smx[t] = mx; ssm[t] = sm;
  __syncthreads();
  if (half == 0){
    mx = fmaxf(mx, smx[t + 128]);
    sm += ssm[t + 128];
    size_t o = ((size_t)g * PS + s) * 128 + f;
    pmax[o] = mx;
    psum[o] = sm;
  }
}

__global__ __launch_bounds__(128) void pool_reduce(
    const float* __restrict__ pmax, const float* __restrict__ psum,
    const int* __restrict__ batch, int n, float* __restrict__ Fp)
{
  int g = blockIdx.x;
  int f = threadIdx.x;
  int lo = 0, hi = n;
  while (lo < hi){ int mid = (lo + hi) >> 1; if (batch[mid] < g) lo = mid + 1; else hi = mid; }
  int s0 = lo;
  lo = s0; hi = n;
  while (lo < hi){ int mid = (lo + hi) >> 1; if (batch[mid] < g + 1) lo = mid + 1; else hi = mid; }
  int cnt = lo - s0;

  float mx = -INFINITY, sm = 0.f;
#pragma unroll
  for (int s = 0; s < PS; ++s){
    size_t o = ((size_t)g * PS + s) * 128 + f;
    mx = fmaxf(mx, pmax[o]);
    sm += psum[o];
  }
  float mean = sm / fmaxf((float)cnt, 1.0f);
  Fp[(size_t)g * 256 + f]       = mx;
  Fp[(size_t)g * 256 + 128 + f] = mean;
}

// ---------------------------------------------------------------------------
// MLP head (parallel)
// ---------------------------------------------------------------------------
__global__ __launch_bounds__(256) void head_gemm1(
    const float* __restrict__ Fp, const float* __restrict__ W1,
    const float* __restrict__ b1, float* __restrict__ A1)
{
  int idx = blockIdx.x * 256 + threadIdx.x;
  int r = idx >> 7, c = idx & 127;
  const float4* f4 = (const float4*)(Fp + r * 256);
  const float4* w4 = (const float4*)(W1 + c * 256);
  float acc = b1[c];
#pragma unroll
  for (int k = 0; k < 64; ++k) acc += dot4(f4[k], w4[k]);
  A1[idx] = acc;
}

__global__ __launch_bounds__(256) void head_bn_relu1(
    const float* __restrict__ A1, const float* __restrict__ g1,
    const float* __restrict__ be1, float* __restrict__ H1n)
{
  __shared__ float sMS[256];
  int t = threadIdx.x;
  if (t < 128){
    float m = 0.f, m2 = 0.f;
    for (int r = 0; r < 64; ++r){ float v = A1[r * 128 + t]; m += v; m2 += v * v; }
    m *= (1.f / 64.f); m2 *= (1.f / 64.f);
    float var = m2 - m * m;
    sMS[t] = m;
    sMS[128 + t] = g1[t] * rsqrtf(var + 1e-5f);
  }
  __syncthreads();
  for (int i = t; i < 64 * 128; i += 256){
    int c = i & 127;
    float v = (A1[i] - sMS[c]) * sMS[128 + c] + be1[c];
    H1n[i] = fmaxf(v, 0.f);
  }
}

__global__ __launch_bounds__(256) void head_gemm2(
    const float* __restrict__ H1n, const float* __restrict__ W2,
    const float* __restrict__ b2, float* __restrict__ A2)
{
  int idx = blockIdx.x * 256 + threadIdx.x;
  int r = idx >> 6, c = idx & 63;
  const float4* f4 = (const float4*)(H1n + r * 128);
  const float4* w4 = (const float4*)(W2 + c * 128);
  float acc = b2[c];
#pragma unroll
  for (int k = 0; k < 32; ++k) acc += dot4(f4[k], w4[k]);
  A2[idx] = acc;
}

__global__ __launch_bounds__(256) void head_tail(
    const float* __restrict__ A2, const float* __restrict__ g2,
    const float* __restrict__ be2, const float* __restrict__ W3,
    const float* __restrict__ b3, float* __restrict__ out)
{
  __shared__ float sH[64 * 64];
  __shared__ float sMS[128];
  int t = threadIdx.x;
  for (int i = t; i < 64 * 64 / 4; i += 256)
    ((float4*)sH)[i] = ((const float4*)A2)[i];
  __syncthreads();
  if (t < 64){
    float m = 0.f, m2 = 0.f;
    for (int r = 0; r < 64; ++r){ float v = sH[r * 64 + t]; m += v; m2 += v * v; }
    m *= (1.f / 64.f); m2 *= (1.f / 64.f);
    float var = m2 - m * m;
    sMS[t] = m;
    sMS[64 + t] = g2[t] * rsqrtf(var + 1e-5f);
  }
  __syncthreads();
  for (int i = t; i < 64 * 64; i += 256){
    int c = i & 63;
    float v = (sH[i] - sMS[c]) * sMS[64 + c] + be2[c];
    sH[i] = fmaxf(v, 0.f);
  }
  __syncthreads();
  if (t < 64){
    float acc = b3[0];
#pragma unroll
    for (int k = 0; k < 64; ++k) acc += sH[t * 64 + k] * W3[k];
    out[t] = acc;
  }
}

// ---------------------------------------------------------------------------
extern "C" void kernel_launch(void* const* d_in, const int* in_sizes, int n_in,
                              void* d_out, int out_size, void* d_ws, size_t ws_size,
                              hipStream_t stream)
{
  const float* x     = (const float*)d_in[0];
  const int*   ei    = (const int*)d_in[1];
  const int*   batch = (const int*)d_in[2];

  const float* l0Wk = (const float*)d_in[3];  const float* l0bk = (const float*)d_in[4];
  const float* l0Wq = (const float*)d_in[5];  const float* l0bq = (const float*)d_in[6];
  const float* l0Wv = (const float*)d_in[7];  const float* l0bv = (const float*)d_in[8];
  const float* l0Ws = (const float*)d_in[9];  const float* l0bs = (const float*)d_in[10];
  const float* l1Wk = (const float*)d_in[11]; const float* l1bk = (const float*)d_in[12];
  const float* l1Wq = (const float*)d_in[13]; const float* l1bq = (const float*)d_in[14];
  const float* l1Wv = (const float*)d_in[15]; const float* l1bv = (const float*)d_in[16];
  const float* l1Ws = (const float*)d_in[17]; const float* l1bs = (const float*)d_in[18];

  const float* W1  = (const float*)d_in[19]; const float* b1  = (const float*)d_in[20];
  const float* g1  = (const float*)d_in[21]; const float* be1 = (const float*)d_in[22];
  const float* W2  = (const float*)d_in[23]; const float* b2  = (const float*)d_in[24];
  const float* g2  = (const float*)d_in[25]; const float* be2 = (const float*)d_in[26];
  const float* W3  = (const float*)d_in[27]; const float* b3  = (const float*)d_in[28];

  const int N = in_sizes[0] / HH;
  const int E = in_sizes[1] / 2;
  const int G = out_size;
  const size_t NH = (size_t)N * HH;

  float* ws = (float*)d_ws;
  float* K  = ws;
  float* Q  = K  + NH;
  float* V  = Q  + NH;
  float* H0 = V  + NH;
  float* H1 = H0 + NH;
  float* Fp = H1 + NH;                          // G*256
  float* A1  = Fp + (size_t)G * 256;            // 64*128
  float* H1n = A1 + 64 * 128;
  float* A2  = H1n + 64 * 128;                  // 64*64
  float* pmax = A2 + 64 * 64;                   // G*PS*128
  float* psum = pmax + (size_t)G * PS * 128;    // G*PS*128
  int* ip        = (int*)(psum + (size_t)G * PS * 128);
  int* row_start = ip;                 // N+1
  int* cursor    = row_start + (N + 1);
  int* cnt       = cursor + N;
  int* csr_src   = cnt + N;            // E
  int* bsum      = csr_src + E;        // 256

  const int nb   = (N + 255) / 256;
  const int ebl  = (E + 255) / 256;
  const dim3 gemm_grid((N + 127) / 128, 4);
  const int agg_blocks = (N + 3) / 4;

  // --- CSR build ---
  zero_int<<<nb, 256, 0, stream>>>(cnt, N);
  hist_dst<<<ebl, 256, 0, stream>>>(ei, E, cnt);
  scan1<<<nb, 256, 0, stream>>>(cnt, N, row_start, bsum);
  scan2<<<1, 256, 0, stream>>>(bsum, nb);
  scan3<<<(N + 256) / 256, 256, 0, stream>>>(row_start, bsum, N, E, cursor);
  scatter_src<<<ebl, 256, 0, stream>>>(ei, E, cursor, csr_src);

  // --- Layer 0 ---
  gemm_tile<false><<<gemm_grid, 256, 0, stream>>>(
      x, l0Wk, l0bk, l0Wq, l0bq, l0Wv, l0bv, l0Ws, l0bs, K, Q, V, H0, N);
  node_agg<<<agg_blocks, 256, 0, stream>>>(K, Q, V, H0, row_start, csr_src, N, H0);

  // --- Layer 1 ---
  gemm_tile<true><<<gemm_grid, 256, 0, stream>>>(
      H0, l1Wk, l1bk, l1Wq, l1bq, l1Wv, l1bv, l1Ws, l1bs, K, Q, V, H1, N);
  node_agg<<<agg_blocks, 256, 0, stream>>>(K, Q, V, H1, row_start, csr_src, N, H1);

  // --- Pool (two-phase) + head ---
  pool_partial<<<dim3(G, PS), 256, 0, stream>>>(H1, batch, N, pmax, psum);
  pool_reduce<<<G, 128, 0, stream>>>(pmax, psum, batch, N, Fp);
  head_gemm1<<<32, 256, 0, stream>>>(Fp, W1, b1, A1);
  head_bn_relu1<<<1, 256, 0, stream>>>(A1, g1, be1, H1n);
  head_gemm2<<<16, 256, 0, stream>>>(H1n, W2, b2, A2);
  head_tail<<<1, 256, 0, stream>>>(A2, g2, be2, W3, b3, (float*)d_out);
}

// Round 6
// 651.895 us; speedup vs baseline: 1.0708x; 1.0708x over previous
//
#include <hip/hip_runtime.h>
#include <math.h>

#define HH 128   // hidden dim (both layers) == input F
#define PS 16    // pool slices per graph
#define SXS 36   // LDS row stride in floats: 36 % 32 = 4 -> bank rotation/row

__device__ __forceinline__ float dot4(float4 a, float4 b){
  return a.x*b.x + a.y*b.y + a.z*b.z + a.w*b.w;
}

// ---------------------------------------------------------------------------
// GEMM v4: out = X @ W.T + b for one of {K,Q,V,skip} (m = blockIdx.x & 3;
// consecutive blocks share the same X row-tile -> X stays L2-hot).
// Tile: BM=128 rows x 128 cols, BK=32 (4 chunks of K=128).
// 256 threads, each owns 8x8 outputs at rows ty+16i, cols tx+16j (strided
// mapping + stride-36 LDS rows -> measured-0-conflict bank pattern from r4).
// Inner loop: explicit fmaf chains -> 1 v_fma_f32 per MAC.
// ---------------------------------------------------------------------------
template<bool RELU>
__global__ __launch_bounds__(256, 2) void gemm_tile(
    const float* __restrict__ X,
    const float* __restrict__ Wk, const float* __restrict__ bk,
    const float* __restrict__ Wq, const float* __restrict__ bq,
    const float* __restrict__ Wv, const float* __restrict__ bv,
    const float* __restrict__ Ws, const float* __restrict__ bs,
    float* __restrict__ Ko, float* __restrict__ Qo,
    float* __restrict__ Vo, float* __restrict__ So, int n)
{
  __shared__ float sX[128 * SXS];   // 18.4 KB
  __shared__ float sW[128 * SXS];   // 18.4 KB

  const int m = blockIdx.x & 3;
  const float* W; const float* B; float* D;
  if (m == 0){ W = Wk; B = bk; D = Ko; }
  else if (m == 1){ W = Wq; B = bq; D = Qo; }
  else if (m == 2){ W = Wv; B = bv; D = Vo; }
  else { W = Ws; B = bs; D = So; }

  const int tid = threadIdx.x;
  const int tx = tid & 15;        // cols tx + 16j, j=0..7
  const int ty = tid >> 4;        // rows ty + 16i, i=0..7
  const int row0 = (blockIdx.x >> 2) * 128;

  float acc[8][8];
#pragma unroll
  for (int i = 0; i < 8; ++i)
#pragma unroll
    for (int j = 0; j < 8; ++j) acc[i][j] = 0.f;

  for (int kc = 0; kc < 4; ++kc){
    // ---- stage X chunk: 128 rows x 8 float4 ----
#pragma unroll
    for (int it = 0; it < 4; ++it){
      int fi = tid + it * 256;
      int r = fi >> 3, kq = fi & 7;
      int gr = row0 + r;
      float4 v = make_float4(0.f, 0.f, 0.f, 0.f);
      if (gr < n){
        v = ((const float4*)X)[(size_t)gr * 32 + kc * 8 + kq];
        if (RELU){
          v.x = fmaxf(v.x, 0.f); v.y = fmaxf(v.y, 0.f);
          v.z = fmaxf(v.z, 0.f); v.w = fmaxf(v.w, 0.f);
        }
      }
      *(float4*)&sX[r * SXS + kq * 4] = v;
    }
    // ---- stage W chunk: 128 cols x 8 float4 ----
#pragma unroll
    for (int it = 0; it < 4; ++it){
      int fi = tid + it * 256;
      int c = fi >> 3, kq = fi & 7;
      float4 v = ((const float4*)W)[c * 32 + kc * 8 + kq];
      *(float4*)&sW[c * SXS + kq * 4] = v;
    }
    __syncthreads();

    // ---- compute: 8 k-steps of 4 ----
#pragma unroll
    for (int kq = 0; kq < 8; ++kq){
      float4 a[8], w[8];
#pragma unroll
      for (int i = 0; i < 8; ++i)
        a[i] = *(const float4*)&sX[(ty + 16 * i) * SXS + kq * 4];
#pragma unroll
      for (int j = 0; j < 8; ++j)
        w[j] = *(const float4*)&sW[(tx + 16 * j) * SXS + kq * 4];
#pragma unroll
      for (int i = 0; i < 8; ++i)
#pragma unroll
        for (int j = 0; j < 8; ++j){
          float s = acc[i][j];
          s = fmaf(a[i].x, w[j].x, s);
          s = fmaf(a[i].y, w[j].y, s);
          s = fmaf(a[i].z, w[j].z, s);
          s = fmaf(a[i].w, w[j].w, s);
          acc[i][j] = s;
        }
    }
    __syncthreads();
  }

  // ---- epilogue: bias + store ----
  float bj[8];
#pragma unroll
  for (int j = 0; j < 8; ++j) bj[j] = B[tx + 16 * j];
#pragma unroll
  for (int i = 0; i < 8; ++i){
    int gr = row0 + ty + 16 * i;
    if (gr < n){
      float* dst = D + (size_t)gr * HH;
#pragma unroll
      for (int j = 0; j < 8; ++j)
        dst[tx + 16 * j] = acc[i][j] + bj[j];
    }
  }
}

// ---------------------------------------------------------------------------
// CSR build
// ---------------------------------------------------------------------------
__global__ void zero_int(int* __restrict__ p, int n){
  int i = blockIdx.x * blockDim.x + threadIdx.x;
  if (i < n) p[i] = 0;
}

__global__ void hist_dst(const int* __restrict__ ei, int E, int* __restrict__ cnt){
  int e = blockIdx.x * blockDim.x + threadIdx.x;
  if (e < E) atomicAdd(&cnt[ei[E + e]], 1);
}

__global__ __launch_bounds__(256) void scan1(const int* __restrict__ cnt, int n,
                                             int* __restrict__ excl, int* __restrict__ bsum){
  __shared__ int s[256];
  int t = threadIdx.x;
  int i = blockIdx.x * 256 + t;
  int v = (i < n) ? cnt[i] : 0;
  s[t] = v;
  __syncthreads();
  for (int off = 1; off < 256; off <<= 1){
    int u = (t >= off) ? s[t - off] : 0;
    __syncthreads();
    s[t] += u;
    __syncthreads();
  }
  if (i < n) excl[i] = s[t] - v;
  if (t == 255) bsum[blockIdx.x] = s[255];
}

__global__ __launch_bounds__(256) void scan2(int* __restrict__ bsum, int nb){
  __shared__ int s[256];
  int t = threadIdx.x;
  int v = (t < nb) ? bsum[t] : 0;
  s[t] = v;
  __syncthreads();
  for (int off = 1; off < 256; off <<= 1){
    int u = (t >= off) ? s[t - off] : 0;
    __syncthreads();
    s[t] += u;
    __syncthreads();
  }
  if (t < nb) bsum[t] = s[t] - v;
}

__global__ void scan3(int* __restrict__ row_start, const int* __restrict__ bsum,
                      int n, int E, int* __restrict__ cursor){
  int i = blockIdx.x * blockDim.x + threadIdx.x;
  if (i < n){
    int v = row_start[i] + bsum[i >> 8];
    row_start[i] = v;
    cursor[i] = v;
  }
  if (i == n) row_start[n] = E;
}

__global__ void scatter_src(const int* __restrict__ ei, int E,
                            int* __restrict__ cursor, int* __restrict__ csr_src){
  int e = blockIdx.x * blockDim.x + threadIdx.x;
  if (e < E){
    int d = ei[E + e];
    int pos = atomicAdd(&cursor[d], 1);
    csr_src[pos] = ei[e];
  }
}

// ---------------------------------------------------------------------------
// Node-centric aggregate: one wave per dst node, float2 per lane.
// ---------------------------------------------------------------------------
__global__ __launch_bounds__(256) void node_agg(
    const float* __restrict__ Kx, const float* __restrict__ Qx,
    const float* __restrict__ Vx, const float* __restrict__ Sx,
    const int* __restrict__ row_start, const int* __restrict__ csr_src,
    int n, float* __restrict__ H)
{
  int w = blockIdx.x * 4 + (threadIdx.x >> 6);
  w = __builtin_amdgcn_readfirstlane(w);
  if (w >= n) return;
  int lane = threadIdx.x & 63;

  float2 kd = ((const float2*)(Kx + (size_t)w * HH))[lane];
  float ax = 0.f, ay = 0.f;
  int j = row_start[w];
  const int jend = row_start[w + 1];
  for (; j + 1 < jend; j += 2){
    int sA = csr_src[j], sB = csr_src[j + 1];
    float2 qa = ((const float2*)(Qx + (size_t)sA * HH))[lane];
    float2 va = ((const float2*)(Vx + (size_t)sA * HH))[lane];
    float2 qb = ((const float2*)(Qx + (size_t)sB * HH))[lane];
    float2 vb = ((const float2*)(Vx + (size_t)sB * HH))[lane];
    float gax = 1.f / (1.f + __expf(-(kd.x + qa.x)));
    float gay = 1.f / (1.f + __expf(-(kd.y + qa.y)));
    float gbx = 1.f / (1.f + __expf(-(kd.x + qb.x)));
    float gby = 1.f / (1.f + __expf(-(kd.y + qb.y)));
    ax += gax * va.x + gbx * vb.x;
    ay += gay * va.y + gby * vb.y;
  }
  if (j < jend){
    int sA = csr_src[j];
    float2 qa = ((const float2*)(Qx + (size_t)sA * HH))[lane];
    float2 va = ((const float2*)(Vx + (size_t)sA * HH))[lane];
    ax += va.x / (1.f + __expf(-(kd.x + qa.x)));
    ay += va.y / (1.f + __expf(-(kd.y + qa.y)));
  }
  float2 sk = ((const float2*)(Sx + (size_t)w * HH))[lane];
  float2 o; o.x = ax + sk.x; o.y = ay + sk.y;
  ((float2*)(H + (size_t)w * HH))[lane] = o;
}

// ---------------------------------------------------------------------------
// Pool, two-phase.
// ---------------------------------------------------------------------------
__global__ __launch_bounds__(256) void pool_partial(
    const float* __restrict__ Hn, const int* __restrict__ batch,
    int n, float* __restrict__ pmax, float* __restrict__ psum)
{
  int g = blockIdx.x;
  int s = blockIdx.y;
  int lo = 0, hi = n;
  while (lo < hi){ int mid = (lo + hi) >> 1; if (batch[mid] < g) lo = mid + 1; else hi = mid; }
  int s0 = lo;
  lo = s0; hi = n;
  while (lo < hi){ int mid = (lo + hi) >> 1; if (batch[mid] < g + 1) lo = mid + 1; else hi = mid; }
  int e0 = lo;

  int len = e0 - s0;
  int a0 = s0 + (int)(((long long)len * s) / PS);
  int a1 = s0 + (int)(((long long)len * (s + 1)) / PS);

  int t = threadIdx.x;
  int f = t & 127;
  int half = t >> 7;
  float mx = -INFINITY;
  float sm = 0.f;
  for (int i = a0 + half; i < a1; i += 2){
    float v = Hn[(size_t)i * HH + f];
    mx = fmaxf(mx, v);
    sm += v;
  }
  __shared__ float smx[256], ssm[256];
  smx[t] = mx; ssm[t] = sm;
  __syncthreads();
  if (half == 0){
    mx = fmaxf(mx, smx[t + 128]);
    sm += ssm[t + 128];
    size_t o = ((size_t)g * PS + s) * 128 + f;
    pmax[o] = mx;
    psum[o] = sm;
  }
}

__global__ __launch_bounds__(128) void pool_reduce(
    const float* __restrict__ pmax, const float* __restrict__ psum,
    const int* __restrict__ batch, int n, float* __restrict__ Fp)
{
  int g = blockIdx.x;
  int f = threadIdx.x;
  int lo = 0, hi = n;
  while (lo < hi){ int mid = (lo + hi) >> 1; if (batch[mid] < g) lo = mid + 1; else hi = mid; }
  int s0 = lo;
  lo = s0; hi = n;
  while (lo < hi){ int mid = (lo + hi) >> 1; if (batch[mid] < g + 1) lo = mid + 1; else hi = mid; }
  int cnt = lo - s0;

  float mx = -INFINITY, sm = 0.f;
#pragma unroll
  for (int s = 0; s < PS; ++s){
    size_t o = ((size_t)g * PS + s) * 128 + f;
    mx = fmaxf(mx, pmax[o]);
    sm += psum[o];
  }
  float mean = sm / fmaxf((float)cnt, 1.0f);
  Fp[(size_t)g * 256 + f]       = mx;
  Fp[(size_t)g * 256 + 128 + f] = mean;
}

// ---------------------------------------------------------------------------
// MLP head (parallel)
// ---------------------------------------------------------------------------
__global__ __launch_bounds__(256) void head_gemm1(
    const float* __restrict__ Fp, const float* __restrict__ W1,
    const float* __restrict__ b1, float* __restrict__ A1)
{
  int idx = blockIdx.x * 256 + threadIdx.x;
  int r = idx >> 7, c = idx & 127;
  const float4* f4 = (const float4*)(Fp + r * 256);
  const float4* w4 = (const float4*)(W1 + c * 256);
  float acc = b1[c];
#pragma unroll
  for (int k = 0; k < 64; ++k) acc += dot4(f4[k], w4[k]);
  A1[idx] = acc;
}

__global__ __launch_bounds__(256) void head_bn_relu1(
    const float* __restrict__ A1, const float* __restrict__ g1,
    const float* __restrict__ be1, float* __restrict__ H1n)
{
  __shared__ float sMS[256];
  int t = threadIdx.x;
  if (t < 128){
    float m = 0.f, m2 = 0.f;
    for (int r = 0; r < 64; ++r){ float v = A1[r * 128 + t]; m += v; m2 += v * v; }
    m *= (1.f / 64.f); m2 *= (1.f / 64.f);
    float var = m2 - m * m;
    sMS[t] = m;
    sMS[128 + t] = g1[t] * rsqrtf(var + 1e-5f);
  }
  __syncthreads();
  for (int i = t; i < 64 * 128; i += 256){
    int c = i & 127;
    float v = (A1[i] - sMS[c]) * sMS[128 + c] + be1[c];
    H1n[i] = fmaxf(v, 0.f);
  }
}

__global__ __launch_bounds__(256) void head_gemm2(
    const float* __restrict__ H1n, const float* __restrict__ W2,
    const float* __restrict__ b2, float* __restrict__ A2)
{
  int idx = blockIdx.x * 256 + threadIdx.x;
  int r = idx >> 6, c = idx & 63;
  const float4* f4 = (const float4*)(H1n + r * 128);
  const float4* w4 = (const float4*)(W2 + c * 128);
  float acc = b2[c];
#pragma unroll
  for (int k = 0; k < 32; ++k) acc += dot4(f4[k], w4[k]);
  A2[idx] = acc;
}

__global__ __launch_bounds__(256) void head_tail(
    const float* __restrict__ A2, const float* __restrict__ g2,
    const float* __restrict__ be2, const float* __restrict__ W3,
    const float* __restrict__ b3, float* __restrict__ out)
{
  __shared__ float sH[64 * 64];
  __shared__ float sMS[128];
  int t = threadIdx.x;
  for (int i = t; i < 64 * 64 / 4; i += 256)
    ((float4*)sH)[i] = ((const float4*)A2)[i];
  __syncthreads();
  if (t < 64){
    float m = 0.f, m2 = 0.f;
    for (int r = 0; r < 64; ++r){ float v = sH[r * 64 + t]; m += v; m2 += v * v; }
    m *= (1.f / 64.f); m2 *= (1.f / 64.f);
    float var = m2 - m * m;
    sMS[t] = m;
    sMS[64 + t] = g2[t] * rsqrtf(var + 1e-5f);
  }
  __syncthreads();
  for (int i = t; i < 64 * 64; i += 256){
    int c = i & 63;
    float v = (sH[i] - sMS[c]) * sMS[64 + c] + be2[c];
    sH[i] = fmaxf(v, 0.f);
  }
  __syncthreads();
  if (t < 64){
    float acc = b3[0];
#pragma unroll
    for (int k = 0; k < 64; ++k) acc += sH[t * 64 + k] * W3[k];
    out[t] = acc;
  }
}

// ---------------------------------------------------------------------------
extern "C" void kernel_launch(void* const* d_in, const int* in_sizes, int n_in,
                              void* d_out, int out_size, void* d_ws, size_t ws_size,
                              hipStream_t stream)
{
  const float* x     = (const float*)d_in[0];
  const int*   ei    = (const int*)d_in[1];
  const int*   batch = (const int*)d_in[2];

  const float* l0Wk = (const float*)d_in[3];  const float* l0bk = (const float*)d_in[4];
  const float* l0Wq = (const float*)d_in[5];  const float* l0bq = (const float*)d_in[6];
  const float* l0Wv = (const float*)d_in[7];  const float* l0bv = (const float*)d_in[8];
  const float* l0Ws = (const float*)d_in[9];  const float* l0bs = (const float*)d_in[10];
  const float* l1Wk = (const float*)d_in[11]; const float* l1bk = (const float*)d_in[12];
  const float* l1Wq = (const float*)d_in[13]; const float* l1bq = (const float*)d_in[14];
  const float* l1Wv = (const float*)d_in[15]; const float* l1bv = (const float*)d_in[16];
  const float* l1Ws = (const float*)d_in[17]; const float* l1bs = (const float*)d_in[18];

  const float* W1  = (const float*)d_in[19]; const float* b1  = (const float*)d_in[20];
  const float* g1  = (const float*)d_in[21]; const float* be1 = (const float*)d_in[22];
  const float* W2  = (const float*)d_in[23]; const float* b2  = (const float*)d_in[24];
  const float* g2  = (const float*)d_in[25]; const float* be2 = (const float*)d_in[26];
  const float* W3  = (const float*)d_in[27]; const float* b3  = (const float*)d_in[28];

  const int N = in_sizes[0] / HH;
  const int E = in_sizes[1] / 2;
  const int G = out_size;
  const size_t NH = (size_t)N * HH;

  float* ws = (float*)d_ws;
  float* K  = ws;
  float* Q  = K  + NH;
  float* V  = Q  + NH;
  float* H0 = V  + NH;
  float* H1 = H0 + NH;
  float* Fp = H1 + NH;                          // G*256
  float* A1  = Fp + (size_t)G * 256;            // 64*128
  float* H1n = A1 + 64 * 128;
  float* A2  = H1n + 64 * 128;                  // 64*64
  float* pmax = A2 + 64 * 64;                   // G*PS*128
  float* psum = pmax + (size_t)G * PS * 128;    // G*PS*128
  int* ip        = (int*)(psum + (size_t)G * PS * 128);
  int* row_start = ip;                 // N+1
  int* cursor    = row_start + (N + 1);
  int* cnt       = cursor + N;
  int* csr_src   = cnt + N;            // E
  int* bsum      = csr_src + E;        // 256

  const int nb   = (N + 255) / 256;
  const int ebl  = (E + 255) / 256;
  const int gemm_blocks = ((N + 127) / 128) * 4;   // 4 matrices interleaved
  const int agg_blocks = (N + 3) / 4;

  // --- CSR build ---
  zero_int<<<nb, 256, 0, stream>>>(cnt, N);
  hist_dst<<<ebl, 256, 0, stream>>>(ei, E, cnt);
  scan1<<<nb, 256, 0, stream>>>(cnt, N, row_start, bsum);
  scan2<<<1, 256, 0, stream>>>(bsum, nb);
  scan3<<<(N + 256) / 256, 256, 0, stream>>>(row_start, bsum, N, E, cursor);
  scatter_src<<<ebl, 256, 0, stream>>>(ei, E, cursor, csr_src);

  // --- Layer 0 ---
  gemm_tile<false><<<gemm_blocks, 256, 0, stream>>>(
      x, l0Wk, l0bk, l0Wq, l0bq, l0Wv, l0bv, l0Ws, l0bs, K, Q, V, H0, N);
  node_agg<<<agg_blocks, 256, 0, stream>>>(K, Q, V, H0, row_start, csr_src, N, H0);

  // --- Layer 1 ---
  gemm_tile<true><<<gemm_blocks, 256, 0, stream>>>(
      H0, l1Wk, l1bk, l1Wq, l1bq, l1Wv, l1bv, l1Ws, l1bs, K, Q, V, H1, N);
  node_agg<<<agg_blocks, 256, 0, stream>>>(K, Q, V, H1, row_start, csr_src, N, H1);

  // --- Pool (two-phase) + head ---
  pool_partial<<<dim3(G, PS), 256, 0, stream>>>(H1, batch, N, pmax, psum);
  pool_reduce<<<G, 128, 0, stream>>>(pmax, psum, batch, N, Fp);
  head_gemm1<<<32, 256, 0, stream>>>(Fp, W1, b1, A1);
  head_bn_relu1<<<1, 256, 0, stream>>>(A1, g1, be1, H1n);
  head_gemm2<<<16, 256, 0, stream>>>(H1n, W2, b2, A2);
  head_tail<<<1, 256, 0, stream>>>(A2, g2, be2, W3, b3, (float*)d_out);
}

// Round 7
// 617.113 us; speedup vs baseline: 1.1311x; 1.0564x over previous
//
#include <hip/hip_runtime.h>
#include <math.h>

#define HH 128   // hidden dim (both layers) == input F
#define PS 16    // pool slices per graph

__device__ __forceinline__ float dot4(float4 a, float4 b){
  return a.x*b.x + a.y*b.y + a.z*b.z + a.w*b.w;
}

// ---------------------------------------------------------------------------
// GEMM v5: round-4 proven layout (measured 0 bank conflicts, VALUBusy 70%),
// with ONE change: inner loop uses explicit fmaf chains (4 insts / 4 MACs
// instead of mul+3fma+add = 5).
// Tile: BM=64 rows x 128 cols, BK=64 (2 chunks of K=128). LDS stride 68
// (68 mod 32 = 4 -> bank rotation per row, measured conflict-free).
// m = blockIdx.x & 3 selects {K,Q,V,skip}; consecutive blocks share the
// X row-tile -> X stays L2/L3-hot (FETCH ~51 MB, measured).
// ---------------------------------------------------------------------------
template<bool RELU>
__global__ __launch_bounds__(256) void gemm_tile(
    const float* __restrict__ X,
    const float* __restrict__ Wk, const float* __restrict__ bk,
    const float* __restrict__ Wq, const float* __restrict__ bq,
    const float* __restrict__ Wv, const float* __restrict__ bv,
    const float* __restrict__ Ws, const float* __restrict__ bs,
    float* __restrict__ Ko, float* __restrict__ Qo,
    float* __restrict__ Vo, float* __restrict__ So, int n)
{
  __shared__ float sX[64 * 68];    // 17.4 KB
  __shared__ float sW[128 * 68];   // 34.8 KB

  const int m = blockIdx.x & 3;
  const float* W; const float* B; float* D;
  if (m == 0){ W = Wk; B = bk; D = Ko; }
  else if (m == 1){ W = Wq; B = bq; D = Qo; }
  else if (m == 2){ W = Wv; B = bv; D = Vo; }
  else { W = Ws; B = bs; D = So; }

  const int tid = threadIdx.x;
  const int tx = tid & 15;       // col group: cols tx + 16j, j=0..7
  const int ty = tid >> 4;       // row group: rows ty + 16i, i=0..3
  const int row0 = (blockIdx.x >> 2) * 64;

  float acc[4][8];
#pragma unroll
  for (int i = 0; i < 4; ++i)
#pragma unroll
    for (int j = 0; j < 8; ++j) acc[i][j] = 0.f;

  for (int kc = 0; kc < 2; ++kc){
    const int k0q = kc * 16;  // float4 offset of this k-chunk
    // stage X chunk: 64 rows x 16 float4
    for (int fi = tid; fi < 64 * 16; fi += 256){
      int r = fi >> 4, kq = fi & 15;
      int gr = row0 + r;
      float4 v = make_float4(0.f, 0.f, 0.f, 0.f);
      if (gr < n){
        v = ((const float4*)X)[(size_t)gr * 32 + k0q + kq];
        if (RELU){
          v.x = fmaxf(v.x, 0.f); v.y = fmaxf(v.y, 0.f);
          v.z = fmaxf(v.z, 0.f); v.w = fmaxf(v.w, 0.f);
        }
      }
      *(float4*)&sX[r * 68 + kq * 4] = v;
    }
    // stage W chunk: 128 cols x 16 float4
    for (int fi = tid; fi < 128 * 16; fi += 256){
      int c = fi >> 4, kq = fi & 15;
      float4 v = ((const float4*)W)[c * 32 + k0q + kq];
      *(float4*)&sW[c * 68 + kq * 4] = v;
    }
    __syncthreads();

    for (int k = 0; k < 64; k += 4){
      float4 a[4], w[8];
#pragma unroll
      for (int i = 0; i < 4; ++i)
        a[i] = *(const float4*)&sX[(ty + 16 * i) * 68 + k];
#pragma unroll
      for (int j = 0; j < 8; ++j)
        w[j] = *(const float4*)&sW[(tx + 16 * j) * 68 + k];
#pragma unroll
      for (int i = 0; i < 4; ++i)
#pragma unroll
        for (int j = 0; j < 8; ++j){
          float s = acc[i][j];
          s = fmaf(a[i].x, w[j].x, s);
          s = fmaf(a[i].y, w[j].y, s);
          s = fmaf(a[i].z, w[j].z, s);
          s = fmaf(a[i].w, w[j].w, s);
          acc[i][j] = s;
        }
    }
    __syncthreads();
  }

#pragma unroll
  for (int i = 0; i < 4; ++i){
    int gr = row0 + ty + 16 * i;
    if (gr < n){
#pragma unroll
      for (int j = 0; j < 8; ++j){
        int c = tx + 16 * j;
        D[(size_t)gr * HH + c] = acc[i][j] + B[c];
      }
    }
  }
}

// ---------------------------------------------------------------------------
// CSR build
// ---------------------------------------------------------------------------
__global__ void zero_int(int* __restrict__ p, int n){
  int i = blockIdx.x * blockDim.x + threadIdx.x;
  if (i < n) p[i] = 0;
}

__global__ void hist_dst(const int* __restrict__ ei, int E, int* __restrict__ cnt){
  int e = blockIdx.x * blockDim.x + threadIdx.x;
  if (e < E) atomicAdd(&cnt[ei[E + e]], 1);
}

__global__ __launch_bounds__(256) void scan1(const int* __restrict__ cnt, int n,
                                             int* __restrict__ excl, int* __restrict__ bsum){
  __shared__ int s[256];
  int t = threadIdx.x;
  int i = blockIdx.x * 256 + t;
  int v = (i < n) ? cnt[i] : 0;
  s[t] = v;
  __syncthreads();
  for (int off = 1; off < 256; off <<= 1){
    int u = (t >= off) ? s[t - off] : 0;
    __syncthreads();
    s[t] += u;
    __syncthreads();
  }
  if (i < n) excl[i] = s[t] - v;
  if (t == 255) bsum[blockIdx.x] = s[255];
}

__global__ __launch_bounds__(256) void scan2(int* __restrict__ bsum, int nb){
  __shared__ int s[256];
  int t = threadIdx.x;
  int v = (t < nb) ? bsum[t] : 0;
  s[t] = v;
  __syncthreads();
  for (int off = 1; off < 256; off <<= 1){
    int u = (t >= off) ? s[t - off] : 0;
    __syncthreads();
    s[t] += u;
    __syncthreads();
  }
  if (t < nb) bsum[t] = s[t] - v;
}

__global__ void scan3(int* __restrict__ row_start, const int* __restrict__ bsum,
                      int n, int E, int* __restrict__ cursor){
  int i = blockIdx.x * blockDim.x + threadIdx.x;
  if (i < n){
    int v = row_start[i] + bsum[i >> 8];
    row_start[i] = v;
    cursor[i] = v;
  }
  if (i == n) row_start[n] = E;
}

__global__ void scatter_src(const int* __restrict__ ei, int E,
                            int* __restrict__ cursor, int* __restrict__ csr_src){
  int e = blockIdx.x * blockDim.x + threadIdx.x;
  if (e < E){
    int d = ei[E + e];
    int pos = atomicAdd(&cursor[d], 1);
    csr_src[pos] = ei[e];
  }
}

// ---------------------------------------------------------------------------
// Node-centric aggregate: one wave per dst node, float2 per lane.
// ---------------------------------------------------------------------------
__global__ __launch_bounds__(256) void node_agg(
    const float* __restrict__ Kx, const float* __restrict__ Qx,
    const float* __restrict__ Vx, const float* __restrict__ Sx,
    const int* __restrict__ row_start, const int* __restrict__ csr_src,
    int n, float* __restrict__ H)
{
  int w = blockIdx.x * 4 + (threadIdx.x >> 6);
  w = __builtin_amdgcn_readfirstlane(w);
  if (w >= n) return;
  int lane = threadIdx.x & 63;

  float2 kd = ((const float2*)(Kx + (size_t)w * HH))[lane];
  float ax = 0.f, ay = 0.f;
  int j = row_start[w];
  const int jend = row_start[w + 1];
  for (; j + 1 < jend; j += 2){
    int sA = csr_src[j], sB = csr_src[j + 1];
    float2 qa = ((const float2*)(Qx + (size_t)sA * HH))[lane];
    float2 va = ((const float2*)(Vx + (size_t)sA * HH))[lane];
    float2 qb = ((const float2*)(Qx + (size_t)sB * HH))[lane];
    float2 vb = ((const float2*)(Vx + (size_t)sB * HH))[lane];
    float gax = 1.f / (1.f + __expf(-(kd.x + qa.x)));
    float gay = 1.f / (1.f + __expf(-(kd.y + qa.y)));
    float gbx = 1.f / (1.f + __expf(-(kd.x + qb.x)));
    float gby = 1.f / (1.f + __expf(-(kd.y + qb.y)));
    ax += gax * va.x + gbx * vb.x;
    ay += gay * va.y + gby * vb.y;
  }
  if (j < jend){
    int sA = csr_src[j];
    float2 qa = ((const float2*)(Qx + (size_t)sA * HH))[lane];
    float2 va = ((const float2*)(Vx + (size_t)sA * HH))[lane];
    ax += va.x / (1.f + __expf(-(kd.x + qa.x)));
    ay += va.y / (1.f + __expf(-(kd.y + qa.y)));
  }
  float2 sk = ((const float2*)(Sx + (size_t)w * HH))[lane];
  float2 o; o.x = ax + sk.x; o.y = ay + sk.y;
  ((float2*)(H + (size_t)w * HH))[lane] = o;
}

// ---------------------------------------------------------------------------
// Pool, two-phase.
// ---------------------------------------------------------------------------
__global__ __launch_bounds__(256) void pool_partial(
    const float* __restrict__ Hn, const int* __restrict__ batch,
    int n, float* __restrict__ pmax, float* __restrict__ psum)
{
  int g = blockIdx.x;
  int s = blockIdx.y;
  int lo = 0, hi = n;
  while (lo < hi){ int mid = (lo + hi) >> 1; if (batch[mid] < g) lo = mid + 1; else hi = mid; }
  int s0 = lo;
  lo = s0; hi = n;
  while (lo < hi){ int mid = (lo + hi) >> 1; if (batch[mid] < g + 1) lo = mid + 1; else hi = mid; }
  int e0 = lo;

  int len = e0 - s0;
  int a0 = s0 + (int)(((long long)len * s) / PS);
  int a1 = s0 + (int)(((long long)len * (s + 1)) / PS);

  int t = threadIdx.x;
  int f = t & 127;
  int half = t >> 7;
  float mx = -INFINITY;
  float sm = 0.f;
  for (int i = a0 + half; i < a1; i += 2){
    float v = Hn[(size_t)i * HH + f];
    mx = fmaxf(mx, v);
    sm += v;
  }
  __shared__ float smx[256], ssm[256];
  smx[t] = mx; ssm[t] = sm;
  __syncthreads();
  if (half == 0){
    mx = fmaxf(mx, smx[t + 128]);
    sm += ssm[t + 128];
    size_t o = ((size_t)g * PS + s) * 128 + f;
    pmax[o] = mx;
    psum[o] = sm;
  }
}

__global__ __launch_bounds__(128) void pool_reduce(
    const float* __restrict__ pmax, const float* __restrict__ psum,
    const int* __restrict__ batch, int n, float* __restrict__ Fp)
{
  int g = blockIdx.x;
  int f = threadIdx.x;
  int lo = 0, hi = n;
  while (lo < hi){ int mid = (lo + hi) >> 1; if (batch[mid] < g) lo = mid + 1; else hi = mid; }
  int s0 = lo;
  lo = s0; hi = n;
  while (lo < hi){ int mid = (lo + hi) >> 1; if (batch[mid] < g + 1) lo = mid + 1; else hi = mid; }
  int cnt = lo - s0;

  float mx = -INFINITY, sm = 0.f;
#pragma unroll
  for (int s = 0; s < PS; ++s){
    size_t o = ((size_t)g * PS + s) * 128 + f;
    mx = fmaxf(mx, pmax[o]);
    sm += psum[o];
  }
  float mean = sm / fmaxf((float)cnt, 1.0f);
  Fp[(size_t)g * 256 + f]       = mx;
  Fp[(size_t)g * 256 + 128 + f] = mean;
}

// ---------------------------------------------------------------------------
// MLP head (parallel)
// ---------------------------------------------------------------------------
__global__ __launch_bounds__(256) void head_gemm1(
    const float* __restrict__ Fp, const float* __restrict__ W1,
    const float* __restrict__ b1, float* __restrict__ A1)
{
  int idx = blockIdx.x * 256 + threadIdx.x;
  int r = idx >> 7, c = idx & 127;
  const float4* f4 = (const float4*)(Fp + r * 256);
  const float4* w4 = (const float4*)(W1 + c * 256);
  float acc = b1[c];
#pragma unroll
  for (int k = 0; k < 64; ++k) acc += dot4(f4[k], w4[k]);
  A1[idx] = acc;
}

__global__ __launch_bounds__(256) void head_bn_relu1(
    const float* __restrict__ A1, const float* __restrict__ g1,
    const float* __restrict__ be1, float* __restrict__ H1n)
{
  __shared__ float sMS[256];
  int t = threadIdx.x;
  if (t < 128){
    float m = 0.f, m2 = 0.f;
    for (int r = 0; r < 64; ++r){ float v = A1[r * 128 + t]; m += v; m2 += v * v; }
    m *= (1.f / 64.f); m2 *= (1.f / 64.f);
    float var = m2 - m * m;
    sMS[t] = m;
    sMS[128 + t] = g1[t] * rsqrtf(var + 1e-5f);
  }
  __syncthreads();
  for (int i = t; i < 64 * 128; i += 256){
    int c = i & 127;
    float v = (A1[i] - sMS[c]) * sMS[128 + c] + be1[c];
    H1n[i] = fmaxf(v, 0.f);
  }
}

__global__ __launch_bounds__(256) void head_gemm2(
    const float* __restrict__ H1n, const float* __restrict__ W2,
    const float* __restrict__ b2, float* __restrict__ A2)
{
  int idx = blockIdx.x * 256 + threadIdx.x;
  int r = idx >> 6, c = idx & 63;
  const float4* f4 = (const float4*)(H1n + r * 128);
  const float4* w4 = (const float4*)(W2 + c * 128);
  float acc = b2[c];
#pragma unroll
  for (int k = 0; k < 32; ++k) acc += dot4(f4[k], w4[k]);
  A2[idx] = acc;
}

__global__ __launch_bounds__(256) void head_tail(
    const float* __restrict__ A2, const float* __restrict__ g2,
    const float* __restrict__ be2, const float* __restrict__ W3,
    const float* __restrict__ b3, float* __restrict__ out)
{
  __shared__ float sH[64 * 64];
  __shared__ float sMS[128];
  int t = threadIdx.x;
  for (int i = t; i < 64 * 64 / 4; i += 256)
    ((float4*)sH)[i] = ((const float4*)A2)[i];
  __syncthreads();
  if (t < 64){
    float m = 0.f, m2 = 0.f;
    for (int r = 0; r < 64; ++r){ float v = sH[r * 64 + t]; m += v; m2 += v * v; }
    m *= (1.f / 64.f); m2 *= (1.f / 64.f);
    float var = m2 - m * m;
    sMS[t] = m;
    sMS[64 + t] = g2[t] * rsqrtf(var + 1e-5f);
  }
  __syncthreads();
  for (int i = t; i < 64 * 64; i += 256){
    int c = i & 63;
    float v = (sH[i] - sMS[c]) * sMS[64 + c] + be2[c];
    sH[i] = fmaxf(v, 0.f);
  }
  __syncthreads();
  if (t < 64){
    float acc = b3[0];
#pragma unroll
    for (int k = 0; k < 64; ++k) acc += sH[t * 64 + k] * W3[k];
    out[t] = acc;
  }
}

// ---------------------------------------------------------------------------
extern "C" void kernel_launch(void* const* d_in, const int* in_sizes, int n_in,
                              void* d_out, int out_size, void* d_ws, size_t ws_size,
                              hipStream_t stream)
{
  const float* x     = (const float*)d_in[0];
  const int*   ei    = (const int*)d_in[1];
  const int*   batch = (const int*)d_in[2];

  const float* l0Wk = (const float*)d_in[3];  const float* l0bk = (const float*)d_in[4];
  const float* l0Wq = (const float*)d_in[5];  const float* l0bq = (const float*)d_in[6];
  const float* l0Wv = (const float*)d_in[7];  const float* l0bv = (const float*)d_in[8];
  const float* l0Ws = (const float*)d_in[9];  const float* l0bs = (const float*)d_in[10];
  const float* l1Wk = (const float*)d_in[11]; const float* l1bk = (const float*)d_in[12];
  const float* l1Wq = (const float*)d_in[13]; const float* l1bq = (const float*)d_in[14];
  const float* l1Wv = (const float*)d_in[15]; const float* l1bv = (const float*)d_in[16];
  const float* l1Ws = (const float*)d_in[17]; const float* l1bs = (const float*)d_in[18];

  const float* W1  = (const float*)d_in[19]; const float* b1  = (const float*)d_in[20];
  const float* g1  = (const float*)d_in[21]; const float* be1 = (const float*)d_in[22];
  const float* W2  = (const float*)d_in[23]; const float* b2  = (const float*)d_in[24];
  const float* g2  = (const float*)d_in[25]; const float* be2 = (const float*)d_in[26];
  const float* W3  = (const float*)d_in[27]; const float* b3  = (const float*)d_in[28];

  const int N = in_sizes[0] / HH;
  const int E = in_sizes[1] / 2;
  const int G = out_size;
  const size_t NH = (size_t)N * HH;

  float* ws = (float*)d_ws;
  float* K  = ws;
  float* Q  = K  + NH;
  float* V  = Q  + NH;
  float* H0 = V  + NH;
  float* H1 = H0 + NH;
  float* Fp = H1 + NH;                          // G*256
  float* A1  = Fp + (size_t)G * 256;            // 64*128
  float* H1n = A1 + 64 * 128;
  float* A2  = H1n + 64 * 128;                  // 64*64
  float* pmax = A2 + 64 * 64;                   // G*PS*128
  float* psum = pmax + (size_t)G * PS * 128;    // G*PS*128
  int* ip        = (int*)(psum + (size_t)G * PS * 128);
  int* row_start = ip;                 // N+1
  int* cursor    = row_start + (N + 1);
  int* cnt       = cursor + N;
  int* csr_src   = cnt + N;            // E
  int* bsum      = csr_src + E;        // 256

  const int nb   = (N + 255) / 256;
  const int ebl  = (E + 255) / 256;
  const int gemm_blocks = ((N + 63) / 64) * 4;   // 4 matrices interleaved
  const int agg_blocks = (N + 3) / 4;

  // --- CSR build ---
  zero_int<<<nb, 256, 0, stream>>>(cnt, N);
  hist_dst<<<ebl, 256, 0, stream>>>(ei, E, cnt);
  scan1<<<nb, 256, 0, stream>>>(cnt, N, row_start, bsum);
  scan2<<<1, 256, 0, stream>>>(bsum, nb);
  scan3<<<(N + 256) / 256, 256, 0, stream>>>(row_start, bsum, N, E, cursor);
  scatter_src<<<ebl, 256, 0, stream>>>(ei, E, cursor, csr_src);

  // --- Layer 0 ---
  gemm_tile<false><<<gemm_blocks, 256, 0, stream>>>(
      x, l0Wk, l0bk, l0Wq, l0bq, l0Wv, l0bv, l0Ws, l0bs, K, Q, V, H0, N);
  node_agg<<<agg_blocks, 256, 0, stream>>>(K, Q, V, H0, row_start, csr_src, N, H0);

  // --- Layer 1 ---
  gemm_tile<true><<<gemm_blocks, 256, 0, stream>>>(
      H0, l1Wk, l1bk, l1Wq, l1bq, l1Wv, l1bv, l1Ws, l1bs, K, Q, V, H1, N);
  node_agg<<<agg_blocks, 256, 0, stream>>>(K, Q, V, H1, row_start, csr_src, N, H1);

  // --- Pool (two-phase) + head ---
  pool_partial<<<dim3(G, PS), 256, 0, stream>>>(H1, batch, N, pmax, psum);
  pool_reduce<<<G, 128, 0, stream>>>(pmax, psum, batch, N, Fp);
  head_gemm1<<<32, 256, 0, stream>>>(Fp, W1, b1, A1);
  head_bn_relu1<<<1, 256, 0, stream>>>(A1, g1, be1, H1n);
  head_gemm2<<<16, 256, 0, stream>>>(H1n, W2, b2, A2);
  head_tail<<<1, 256, 0, stream>>>(A2, g2, be2, W3, b3, (float*)d_out);
}